// Round 9
// baseline (87.044 us; speedup 1.0000x reference)
//
#include <hip/hip_runtime.h>

// ROI Align (B=8, H=32, W=32, C=256 NHWC fp32; R=128 ROIs; 7x7 out, 2x2 samples).
//
// Round 9: round-8 (verified) + column-span trimming.
//  - The sample grid spans 13*stepx+2 columns (stepx in [0.286,1.071]) ->
//    avg ~11 of the 16 static columns are used; the rest were wasted loads
//    (~30-40% of gather). Now: lastci = floor(last sample) - xlo (uniform);
//    break the unrolled column loop past lastci and guard the ring prefetch
//    so columns beyond the span are never loaded.
//  - Everything else identical to round 8: separable vsum per column, packed
//    3-bit consume counts in one u64 SGPR, fmaf-consistent wx reconstruction,
//    depth-4 column ring (slot = col mod 4), dy in {0,1,2} templates,
//    XCD swizzle (blockIdx%8 == batch).

#define NB 8
#define NH 32
#define NW 32
#define NR 128

__device__ __forceinline__ float4 lerp4(float4 a, float4 b, float w) {
    float4 r;
    r.x = a.x + (b.x - a.x) * w;
    r.y = a.y + (b.y - a.y) * w;
    r.z = a.z + (b.z - a.z) * w;
    r.w = a.w + (b.w - a.w) * w;
    return r;
}

template<int DY>
__device__ __forceinline__ void roi_row_proc(
    const float4* __restrict__ basep,     // fm4 + batch offset + lane
    int ro0, int ro1, int ro2, int ro3,   // clamped row offsets (float4 units)
    int xlo, float basex, float stepx,
    float wy0, float wy1,
    float4* __restrict__ outp)            // out4 + (n*49+oy*7)*64 + lane
{
    // Ring of raw row data for 4 columns; slot = column mod 4. All indices
    // compile-time after full unroll (no runtime-indexed register arrays).
    float4 ring[4][4];

#define LOADSLOT(S, cidx) do {                                   \
        int xo_ = (min((cidx), NW - 1)) << 6;                    \
        ring[S][0] = basep[ro0 + xo_];                           \
        ring[S][1] = basep[ro1 + xo_];                           \
        if constexpr (DY >= 1) ring[S][2] = basep[ro2 + xo_];    \
        if constexpr (DY == 2) ring[S][3] = basep[ro3 + xo_];    \
    } while (0)

    // Prologue: columns xlo..xlo+3 into slots 0..3 (span is always >= 5 cols).
    LOADSLOT(0, xlo);
    LOADSLOT(1, xlo + 1);
    LOADSLOT(2, xlo + 2);
    LOADSLOT(3, xlo + 3);

    // Precompute per-column consume counts (overlaps prologue load latency).
    // gi - xlo in [0,14]; <= 4 samples/column (stepx >= 0.286) -> 3 bits each.
    unsigned long long cnt3 = 0;
    int lastci = 0;
    #pragma unroll
    for (int s2 = 0; s2 < 14; ++s2) {
        float xsf = fmaf((float)s2, stepx, basex);
        int gi = __builtin_amdgcn_readfirstlane((int)floorf(xsf));
        cnt3 += 1ull << (3 * (gi - xlo));
        lastci = gi - xlo;                 // floors are monotone; final = max
    }

    auto VSUM = [&](int S) -> float4 {
        float4 lo = lerp4(ring[S][0], ring[S][1], wy0);
        float4 hi;
        if constexpr (DY == 0)      hi = lerp4(ring[S][0], ring[S][1], wy1);
        else if constexpr (DY == 1) hi = lerp4(ring[S][1], ring[S][2], wy1);
        else                        hi = lerp4(ring[S][2], ring[S][3], wy1);
        float4 v;
        v.x = lo.x + hi.x; v.y = lo.y + hi.y;
        v.z = lo.z + hi.z; v.w = lo.w + hi.w;
        return v;
    };

    float4 va = VSUM(0);      // column xlo (slot 0 raw now dead)
    float sf = 0.0f;          // (float)srun, exact
    int srun = 0;
    float4 acc = make_float4(0.f, 0.f, 0.f, 0.f);

    #pragma unroll
    for (int ci = 0; ci < 15; ++ci) {
        if (ci > lastci) break;              // wave-uniform; span exhausted
        float4 vb = VSUM((ci + 1) & 3);      // column ci+1 (prologue or ci-3's prefetch)
        // Refill dead slot ci&3 (held column ci, consumed at iter ci-1) with
        // column xlo+ci+4; it is read at iter ci+3. Only load columns that can
        // actually be consumed: max needed col = xlo + lastci + 1.
        if (ci <= 11 && ci + 4 <= lastci + 1) LOADSLOT(ci & 3, xlo + ci + 4);
        int c = (int)((cnt3 >> (3 * ci)) & 7);
        for (int k = 0; k < c; ++k) {
            float xsf = fmaf(sf, stepx, basex);   // bit-identical to precompute
            float wx = xsf - (float)(xlo + ci);   // exact: floor(xsf)==xlo+ci
            float4 p = lerp4(va, vb, wx);
            if ((srun & 1) == 0) {
                acc = p;
            } else {
                float4 r;
                r.x = (acc.x + p.x) * 0.25f;
                r.y = (acc.y + p.y) * 0.25f;
                r.z = (acc.z + p.z) * 0.25f;
                r.w = (acc.w + p.w) * 0.25f;
                outp[(srun >> 1) << 6] = r;
            }
            ++srun;
            sf += 1.0f;
        }
        va = vb;
    }
#undef LOADSLOT
}

__global__ __launch_bounds__(256) void roi_align_span(
    const float* __restrict__ fm,
    const float* __restrict__ boxes,
    float* __restrict__ out)
{
    int bid = blockIdx.x;
    int newbid = (bid & 7) * 224 + (bid >> 3);   // XCD -> batch locality
    int t = threadIdx.x;
    int lane = t & 63;                           // channel float4 group
    int g = newbid * 4 + (t >> 6);               // wave id 0..7167 = (n, oy)
    int n = (int)(((unsigned)g * 9363u) >> 16);  // g / 7 (exact for g < 7168)
    int oy = g - n * 7;
    int b = n >> 7;

    // Box math — identical to all verified rounds.
    float bx0 = boxes[n * 4 + 0] * (1.0f / 31.0f);
    float by0 = boxes[n * 4 + 1] * (1.0f / 31.0f);
    float bx1 = boxes[n * 4 + 2] * (1.0f / 31.0f);
    float by1 = boxes[n * 4 + 3] * (1.0f / 31.0f);
    float x1 = fmaxf(bx0, 0.0f), y1 = fmaxf(by0, 0.0f);
    float x2 = fminf(bx1, 1.0f), y2 = fminf(by1, 1.0f);
    float bin_h = (y2 - y1) / 7.0f;
    float bin_w = (x2 - x1) / 7.0f;
    float gy1 = y1 + 0.25f * bin_h;
    float gx1 = x1 + 0.25f * bin_w;
    float gy2 = y2 - 0.25f * bin_h;
    float gx2 = x2 - 0.25f * bin_w;
    float basey = gy1 * 31.0f;
    float basex = gx1 * 31.0f;
    float stepy = (gy2 - gy1) * (31.0f / 13.0f);
    float stepx = (gx2 - gx1) * (31.0f / 13.0f);

    // Row geometry for this oy (fixed across all 14 x-samples).
    float ysf0 = basey + (float)(2 * oy) * stepy;
    float ysf1 = basey + (float)(2 * oy + 1) * stepy;
    float f0f = floorf(ysf0);
    float f1f = floorf(ysf1);
    float wy0 = ysf0 - f0f;
    float wy1 = ysf1 - f1f;
    int f0 = (int)f0f;                                        // >= 0, <= 30
    int dy = __builtin_amdgcn_readfirstlane((int)f1f - f0);   // 0, 1, or 2

    const float4* fm4 = (const float4*)fm;
    const float4* basep = fm4 + (size_t)b * (NH * NW * 64) + lane;
    int ro0 = (min(f0,     NH - 1) * NW) << 6;
    int ro1 = (min(f0 + 1, NH - 1) * NW) << 6;
    int ro2 = (min(f0 + 2, NH - 1) * NW) << 6;
    int ro3 = (min(f0 + 3, NH - 1) * NW) << 6;

    int xlo = __builtin_amdgcn_readfirstlane((int)floorf(basex));
    float4* outp = (float4*)out + (n * 49 + oy * 7) * 64 + lane;

    if (dy == 0)      roi_row_proc<0>(basep, ro0, ro1, ro2, ro3, xlo, basex, stepx, wy0, wy1, outp);
    else if (dy == 1) roi_row_proc<1>(basep, ro0, ro1, ro2, ro3, xlo, basex, stepx, wy0, wy1, outp);
    else              roi_row_proc<2>(basep, ro0, ro1, ro2, ro3, xlo, basex, stepx, wy0, wy1, outp);
}

extern "C" void kernel_launch(void* const* d_in, const int* in_sizes, int n_in,
                              void* d_out, int out_size, void* d_ws, size_t ws_size,
                              hipStream_t stream) {
    const float* fm    = (const float*)d_in[0];
    const float* boxes = (const float*)d_in[1];
    float* out = (float*)d_out;

    // 7168 waves = 1024 ROIs x 7 oy-rows; 4 waves/block -> 1792 blocks.
    roi_align_span<<<1792, 256, 0, stream>>>(fm, boxes, out);
}

// Round 10
// 21.289 us; speedup vs baseline: 4.0887x; 4.0887x over previous
//
#include <hip/hip_runtime.h>

// ROI Align (B=8, H=32, W=32, C=256 NHWC fp32; R=128 ROIs; 7x7 out, 2x2 samples).
//
// Round 10: round-8 (verified, 22.4us) + span trimming WITHOUT breaking unroll.
//  - Round 9's data-dependent `break` inside the unrolled loop killed full
//    unrolling -> ring[][] indices became runtime -> scratch spill (VGPR=32,
//    +193MB spill writes, 87us). Lesson: rule #20.
//  - Now: loop stays a static 15-trip full unroll; the ONLY change vs round 8
//    is a wave-uniform predicate on the ring prefetch so columns beyond the
//    sample span (avg ~11 of 16 used) are never loaded. Dead iterations past
//    lastci execute ~12 VALU ops (c=0, no samples) but issue no loads.
//  - Everything else identical to round 8: separable vsum per column, packed
//    3-bit consume counts in one u64 SGPR, fmaf-consistent wx reconstruction,
//    depth-4 column ring (slot = col mod 4), dy in {0,1,2} templates,
//    XCD swizzle (blockIdx%8 == batch).

#define NB 8
#define NH 32
#define NW 32
#define NR 128

__device__ __forceinline__ float4 lerp4(float4 a, float4 b, float w) {
    float4 r;
    r.x = a.x + (b.x - a.x) * w;
    r.y = a.y + (b.y - a.y) * w;
    r.z = a.z + (b.z - a.z) * w;
    r.w = a.w + (b.w - a.w) * w;
    return r;
}

template<int DY>
__device__ __forceinline__ void roi_row_proc(
    const float4* __restrict__ basep,     // fm4 + batch offset + lane
    int ro0, int ro1, int ro2, int ro3,   // clamped row offsets (float4 units)
    int xlo, float basex, float stepx,
    float wy0, float wy1,
    float4* __restrict__ outp)            // out4 + (n*49+oy*7)*64 + lane
{
    // Ring of raw row data for 4 columns; slot = column mod 4. All indices
    // compile-time after full unroll (no runtime-indexed register arrays).
    float4 ring[4][4];

#define LOADSLOT(S, cidx) do {                                   \
        int xo_ = (min((cidx), NW - 1)) << 6;                    \
        ring[S][0] = basep[ro0 + xo_];                           \
        ring[S][1] = basep[ro1 + xo_];                           \
        if constexpr (DY >= 1) ring[S][2] = basep[ro2 + xo_];    \
        if constexpr (DY == 2) ring[S][3] = basep[ro3 + xo_];    \
    } while (0)

    // Prologue: columns xlo..xlo+3 into slots 0..3 (span is always >= ~5 cols).
    LOADSLOT(0, xlo);
    LOADSLOT(1, xlo + 1);
    LOADSLOT(2, xlo + 2);
    LOADSLOT(3, xlo + 3);

    // Precompute per-column consume counts (overlaps prologue load latency).
    // gi - xlo in [0,14]; <= 4 samples/column (stepx >= 0.286) -> 3 bits each.
    unsigned long long cnt3 = 0;
    int lastci = 0;
    #pragma unroll
    for (int s2 = 0; s2 < 14; ++s2) {
        float xsf = fmaf((float)s2, stepx, basex);
        int gi = __builtin_amdgcn_readfirstlane((int)floorf(xsf));
        cnt3 += 1ull << (3 * (gi - xlo));
        lastci = gi - xlo;                 // floors monotone; final = max
    }

    auto VSUM = [&](int S) -> float4 {
        float4 lo = lerp4(ring[S][0], ring[S][1], wy0);
        float4 hi;
        if constexpr (DY == 0)      hi = lerp4(ring[S][0], ring[S][1], wy1);
        else if constexpr (DY == 1) hi = lerp4(ring[S][1], ring[S][2], wy1);
        else                        hi = lerp4(ring[S][2], ring[S][3], wy1);
        float4 v;
        v.x = lo.x + hi.x; v.y = lo.y + hi.y;
        v.z = lo.z + hi.z; v.w = lo.w + hi.w;
        return v;
    };

    float4 va = VSUM(0);      // column xlo (slot 0 raw now dead)
    float sf = 0.0f;          // (float)srun, exact
    int srun = 0;
    float4 acc = make_float4(0.f, 0.f, 0.f, 0.f);

    #pragma unroll
    for (int ci = 0; ci < 15; ++ci) {        // STATIC trip count — no break
        float4 vb = VSUM((ci + 1) & 3);      // column ci+1 (prologue or ci-3's prefetch)
        // Refill dead slot ci&3 with column xlo+ci+4 (read at iter ci+3), but
        // ONLY if that column can be consumed (max needed col = xlo+lastci+1).
        // Wave-uniform predicate; does not perturb the unroll.
        if (ci <= 11 && ci <= lastci - 3) LOADSLOT(ci & 3, xlo + ci + 4);
        int c = (int)((cnt3 >> (3 * ci)) & 7);
        for (int k = 0; k < c; ++k) {
            float xsf = fmaf(sf, stepx, basex);   // bit-identical to precompute
            float wx = xsf - (float)(xlo + ci);   // exact: floor(xsf)==xlo+ci
            float4 p = lerp4(va, vb, wx);
            if ((srun & 1) == 0) {
                acc = p;
            } else {
                float4 r;
                r.x = (acc.x + p.x) * 0.25f;
                r.y = (acc.y + p.y) * 0.25f;
                r.z = (acc.z + p.z) * 0.25f;
                r.w = (acc.w + p.w) * 0.25f;
                outp[(srun >> 1) << 6] = r;
            }
            ++srun;
            sf += 1.0f;
        }
        va = vb;
    }
#undef LOADSLOT
}

__global__ __launch_bounds__(256) void roi_align_span2(
    const float* __restrict__ fm,
    const float* __restrict__ boxes,
    float* __restrict__ out)
{
    int bid = blockIdx.x;
    int newbid = (bid & 7) * 224 + (bid >> 3);   // XCD -> batch locality
    int t = threadIdx.x;
    int lane = t & 63;                           // channel float4 group
    int g = newbid * 4 + (t >> 6);               // wave id 0..7167 = (n, oy)
    int n = (int)(((unsigned)g * 9363u) >> 16);  // g / 7 (exact for g < 7168)
    int oy = g - n * 7;
    int b = n >> 7;

    // Box math — identical to all verified rounds.
    float bx0 = boxes[n * 4 + 0] * (1.0f / 31.0f);
    float by0 = boxes[n * 4 + 1] * (1.0f / 31.0f);
    float bx1 = boxes[n * 4 + 2] * (1.0f / 31.0f);
    float by1 = boxes[n * 4 + 3] * (1.0f / 31.0f);
    float x1 = fmaxf(bx0, 0.0f), y1 = fmaxf(by0, 0.0f);
    float x2 = fminf(bx1, 1.0f), y2 = fminf(by1, 1.0f);
    float bin_h = (y2 - y1) / 7.0f;
    float bin_w = (x2 - x1) / 7.0f;
    float gy1 = y1 + 0.25f * bin_h;
    float gx1 = x1 + 0.25f * bin_w;
    float gy2 = y2 - 0.25f * bin_h;
    float gx2 = x2 - 0.25f * bin_w;
    float basey = gy1 * 31.0f;
    float basex = gx1 * 31.0f;
    float stepy = (gy2 - gy1) * (31.0f / 13.0f);
    float stepx = (gx2 - gx1) * (31.0f / 13.0f);

    // Row geometry for this oy (fixed across all 14 x-samples).
    float ysf0 = basey + (float)(2 * oy) * stepy;
    float ysf1 = basey + (float)(2 * oy + 1) * stepy;
    float f0f = floorf(ysf0);
    float f1f = floorf(ysf1);
    float wy0 = ysf0 - f0f;
    float wy1 = ysf1 - f1f;
    int f0 = (int)f0f;                                        // >= 0, <= 30
    int dy = __builtin_amdgcn_readfirstlane((int)f1f - f0);   // 0, 1, or 2

    const float4* fm4 = (const float4*)fm;
    const float4* basep = fm4 + (size_t)b * (NH * NW * 64) + lane;
    int ro0 = (min(f0,     NH - 1) * NW) << 6;
    int ro1 = (min(f0 + 1, NH - 1) * NW) << 6;
    int ro2 = (min(f0 + 2, NH - 1) * NW) << 6;
    int ro3 = (min(f0 + 3, NH - 1) * NW) << 6;

    int xlo = __builtin_amdgcn_readfirstlane((int)floorf(basex));
    float4* outp = (float4*)out + (n * 49 + oy * 7) * 64 + lane;

    if (dy == 0)      roi_row_proc<0>(basep, ro0, ro1, ro2, ro3, xlo, basex, stepx, wy0, wy1, outp);
    else if (dy == 1) roi_row_proc<1>(basep, ro0, ro1, ro2, ro3, xlo, basex, stepx, wy0, wy1, outp);
    else              roi_row_proc<2>(basep, ro0, ro1, ro2, ro3, xlo, basex, stepx, wy0, wy1, outp);
}

extern "C" void kernel_launch(void* const* d_in, const int* in_sizes, int n_in,
                              void* d_out, int out_size, void* d_ws, size_t ws_size,
                              hipStream_t stream) {
    const float* fm    = (const float*)d_in[0];
    const float* boxes = (const float*)d_in[1];
    float* out = (float*)d_out;

    // 7168 waves = 1024 ROIs x 7 oy-rows; 4 waves/block -> 1792 blocks.
    roi_align_span2<<<1792, 256, 0, stream>>>(fm, boxes, out);
}

// Round 11
// 21.156 us; speedup vs baseline: 4.1144x; 1.0063x over previous
//
#include <hip/hip_runtime.h>

// ROI Align (B=8, H=32, W=32, C=256 NHWC fp32; R=128 ROIs; 7x7 out, 2x2 samples).
//
// Round 11: round-10 (verified, 21.3us) + two latency/locality fixes.
//  (a) NON-TEMPORAL output stores: output is write-once streaming (6.4 MB per
//      XCD through a 4 MiB L2) and was evicting the XCD's 1.05 MB fm slice,
//      making every gather an L3 round-trip. `nt` stores keep fm L2-resident.
//  (b) cnt3/lastci precompute now runs entirely in VALU lanes (all lanes
//      compute identical values) with 3 readfirstlanes at the end, instead of
//      14 serial floor->readfirstlane->SALU round-trips.
//  Everything else identical to round 10: separable vsum per column, packed
//  3-bit consume counts, fmaf-consistent wx reconstruction, depth-4 column
//  ring (slot = col mod 4, static 15-trip unroll, prefetch predicated by
//  wave-uniform span), dy in {0,1,2} templates, XCD swizzle (bid%8 == batch).

#define NB 8
#define NH 32
#define NW 32
#define NR 128

typedef float f32x4 __attribute__((ext_vector_type(4)));

__device__ __forceinline__ float4 lerp4(float4 a, float4 b, float w) {
    float4 r;
    r.x = a.x + (b.x - a.x) * w;
    r.y = a.y + (b.y - a.y) * w;
    r.z = a.z + (b.z - a.z) * w;
    r.w = a.w + (b.w - a.w) * w;
    return r;
}

template<int DY>
__device__ __forceinline__ void roi_row_proc(
    const float4* __restrict__ basep,     // fm4 + batch offset + lane
    int ro0, int ro1, int ro2, int ro3,   // clamped row offsets (float4 units)
    int xlo, float basex, float stepx,
    float wy0, float wy1,
    float4* __restrict__ outp)            // out4 + (n*49+oy*7)*64 + lane
{
    // Ring of raw row data for 4 columns; slot = column mod 4. All indices
    // compile-time after full unroll (no runtime-indexed register arrays).
    float4 ring[4][4];

#define LOADSLOT(S, cidx) do {                                   \
        int xo_ = (min((cidx), NW - 1)) << 6;                    \
        ring[S][0] = basep[ro0 + xo_];                           \
        ring[S][1] = basep[ro1 + xo_];                           \
        if constexpr (DY >= 1) ring[S][2] = basep[ro2 + xo_];    \
        if constexpr (DY == 2) ring[S][3] = basep[ro3 + xo_];    \
    } while (0)

    // Prologue: columns xlo..xlo+3 into slots 0..3 (span is always >= ~5 cols).
    LOADSLOT(0, xlo);
    LOADSLOT(1, xlo + 1);
    LOADSLOT(2, xlo + 2);
    LOADSLOT(3, xlo + 3);

    // Precompute per-column consume counts IN VALU (all lanes identical);
    // 3 readfirstlanes at the end instead of 14 in-chain.
    // gi - xlo in [0,14]; <= 4 samples/column (stepx >= 0.286) -> 3 bits each.
    unsigned long long cnt3v = 0;
    int lastci_v = 0;
    #pragma unroll
    for (int s2 = 0; s2 < 14; ++s2) {
        float xsf = fmaf((float)s2, stepx, basex);
        int gi = (int)floorf(xsf);
        cnt3v += 1ull << (3 * (gi - xlo));
        lastci_v = gi - xlo;               // floors monotone; final = max
    }
    int lastci = __builtin_amdgcn_readfirstlane(lastci_v);
    unsigned c3lo = __builtin_amdgcn_readfirstlane((unsigned)cnt3v);
    unsigned c3hi = __builtin_amdgcn_readfirstlane((unsigned)(cnt3v >> 32));
    unsigned long long cnt3 = ((unsigned long long)c3hi << 32) | c3lo;

    auto VSUM = [&](int S) -> float4 {
        float4 lo = lerp4(ring[S][0], ring[S][1], wy0);
        float4 hi;
        if constexpr (DY == 0)      hi = lerp4(ring[S][0], ring[S][1], wy1);
        else if constexpr (DY == 1) hi = lerp4(ring[S][1], ring[S][2], wy1);
        else                        hi = lerp4(ring[S][2], ring[S][3], wy1);
        float4 v;
        v.x = lo.x + hi.x; v.y = lo.y + hi.y;
        v.z = lo.z + hi.z; v.w = lo.w + hi.w;
        return v;
    };

    float4 va = VSUM(0);      // column xlo (slot 0 raw now dead)
    float sf = 0.0f;          // (float)srun, exact
    int srun = 0;
    float4 acc = make_float4(0.f, 0.f, 0.f, 0.f);

    #pragma unroll
    for (int ci = 0; ci < 15; ++ci) {        // STATIC trip count — no break
        float4 vb = VSUM((ci + 1) & 3);      // column ci+1 (prologue or ci-3's prefetch)
        // Refill dead slot ci&3 with column xlo+ci+4 (read at iter ci+3), but
        // ONLY if that column can be consumed (max needed col = xlo+lastci+1).
        if (ci <= 11 && ci <= lastci - 3) LOADSLOT(ci & 3, xlo + ci + 4);
        int c = (int)((cnt3 >> (3 * ci)) & 7);
        for (int k = 0; k < c; ++k) {
            float xsf = fmaf(sf, stepx, basex);   // bit-identical to precompute
            float wx = xsf - (float)(xlo + ci);   // exact: floor(xsf)==xlo+ci
            float4 p = lerp4(va, vb, wx);
            if ((srun & 1) == 0) {
                acc = p;
            } else {
                f32x4 r;
                r.x = (acc.x + p.x) * 0.25f;
                r.y = (acc.y + p.y) * 0.25f;
                r.z = (acc.z + p.z) * 0.25f;
                r.w = (acc.w + p.w) * 0.25f;
                // Non-temporal: don't pollute L2 with write-once output.
                __builtin_nontemporal_store(r, (f32x4*)(outp + ((srun >> 1) << 6)));
            }
            ++srun;
            sf += 1.0f;
        }
        va = vb;
    }
#undef LOADSLOT
}

__global__ __launch_bounds__(256) void roi_align_nt(
    const float* __restrict__ fm,
    const float* __restrict__ boxes,
    float* __restrict__ out)
{
    int bid = blockIdx.x;
    int newbid = (bid & 7) * 224 + (bid >> 3);   // XCD -> batch locality
    int t = threadIdx.x;
    int lane = t & 63;                           // channel float4 group
    int g = newbid * 4 + (t >> 6);               // wave id 0..7167 = (n, oy)
    int n = (int)(((unsigned)g * 9363u) >> 16);  // g / 7 (exact for g < 7168)
    int oy = g - n * 7;
    int b = n >> 7;

    // Box math — identical to all verified rounds.
    float bx0 = boxes[n * 4 + 0] * (1.0f / 31.0f);
    float by0 = boxes[n * 4 + 1] * (1.0f / 31.0f);
    float bx1 = boxes[n * 4 + 2] * (1.0f / 31.0f);
    float by1 = boxes[n * 4 + 3] * (1.0f / 31.0f);
    float x1 = fmaxf(bx0, 0.0f), y1 = fmaxf(by0, 0.0f);
    float x2 = fminf(bx1, 1.0f), y2 = fminf(by1, 1.0f);
    float bin_h = (y2 - y1) / 7.0f;
    float bin_w = (x2 - x1) / 7.0f;
    float gy1 = y1 + 0.25f * bin_h;
    float gx1 = x1 + 0.25f * bin_w;
    float gy2 = y2 - 0.25f * bin_h;
    float gx2 = x2 - 0.25f * bin_w;
    float basey = gy1 * 31.0f;
    float basex = gx1 * 31.0f;
    float stepy = (gy2 - gy1) * (31.0f / 13.0f);
    float stepx = (gx2 - gx1) * (31.0f / 13.0f);

    // Row geometry for this oy (fixed across all 14 x-samples).
    float ysf0 = basey + (float)(2 * oy) * stepy;
    float ysf1 = basey + (float)(2 * oy + 1) * stepy;
    float f0f = floorf(ysf0);
    float f1f = floorf(ysf1);
    float wy0 = ysf0 - f0f;
    float wy1 = ysf1 - f1f;
    int f0 = (int)f0f;                                        // >= 0, <= 30
    int dy = __builtin_amdgcn_readfirstlane((int)f1f - f0);   // 0, 1, or 2

    const float4* fm4 = (const float4*)fm;
    const float4* basep = fm4 + (size_t)b * (NH * NW * 64) + lane;
    int ro0 = (min(f0,     NH - 1) * NW) << 6;
    int ro1 = (min(f0 + 1, NH - 1) * NW) << 6;
    int ro2 = (min(f0 + 2, NH - 1) * NW) << 6;
    int ro3 = (min(f0 + 3, NH - 1) * NW) << 6;

    int xlo = __builtin_amdgcn_readfirstlane((int)floorf(basex));
    float4* outp = (float4*)out + (n * 49 + oy * 7) * 64 + lane;

    if (dy == 0)      roi_row_proc<0>(basep, ro0, ro1, ro2, ro3, xlo, basex, stepx, wy0, wy1, outp);
    else if (dy == 1) roi_row_proc<1>(basep, ro0, ro1, ro2, ro3, xlo, basex, stepx, wy0, wy1, outp);
    else              roi_row_proc<2>(basep, ro0, ro1, ro2, ro3, xlo, basex, stepx, wy0, wy1, outp);
}

extern "C" void kernel_launch(void* const* d_in, const int* in_sizes, int n_in,
                              void* d_out, int out_size, void* d_ws, size_t ws_size,
                              hipStream_t stream) {
    const float* fm    = (const float*)d_in[0];
    const float* boxes = (const float*)d_in[1];
    float* out = (float*)d_out;

    // 7168 waves = 1024 ROIs x 7 oy-rows; 4 waves/block -> 1792 blocks.
    roi_align_nt<<<1792, 256, 0, stream>>>(fm, boxes, out);
}